// Round 9
// baseline (78.455 us; speedup 1.0000x reference)
//
#include <hip/hip_runtime.h>
#include <hip/hip_bf16.h>
#include <float.h>

#define N_SAMP   1024
#define C_IN     22
#define HW       361
#define C_TRUNK  384
#define HID      128
#define NHIST    5
#define HIST_START 9
#define NGATE    512   // 4*HID

typedef __attribute__((ext_vector_type(8))) short short8v;
typedef __attribute__((ext_vector_type(4))) float float4v;

static __device__ __forceinline__ ushort f2bf(float x) {
  unsigned int b = __float_as_uint(x);
  b += 0x7fffu + ((b >> 16) & 1u);
  return (ushort)(b >> 16);
}
static __device__ __forceinline__ float bf2f(ushort u) {
  return __uint_as_float(((unsigned int)u) << 16);
}

// -------- Kernel 1: fused argmax + gather (+ w_ih -> bf16 precvt) ------------
// 1024 blocks x 384 threads. Phase 1: waves 0..4 reduce history plane t via
// shuffle butterfly -> s_idx/s_mov in LDS. Phase 2: threads 0..191 gather rows
// {c, c+192} (10 scattered loads in flight, same 1444B trunk rows). Blocks
// 0..767 also convert 256 elems of w_ih to bf16 (free, consumed next kernel).
__global__ __launch_bounds__(384) void prep_kernel(
    const float* __restrict__ inp,    // (N, 22, 361)
    const float* __restrict__ w_ih,   // (512, 384)
    const float* __restrict__ trunk,  // (N, 384, 361)
    ushort* __restrict__ w_ihb,       // (512, 384) bf16
    ushort* __restrict__ seq)         // (N, 5, 384) bf16, reversed + masked
{
  const int n    = blockIdx.x;
  const int tid  = threadIdx.x;
  const int wave = tid >> 6;   // 0..5
  const int lane = tid & 63;
  __shared__ int   s_idx[NHIST];
  __shared__ float s_mov[NHIST];

  if (n < 768 && tid < 256) {
    int o = n * 256 + tid;
    w_ihb[o] = f2bf(w_ih[o]);
  }

  if (wave < NHIST) {
    const float* base = inp + ((size_t)n * C_IN + HIST_START + wave) * HW;
    float v = -FLT_MAX; int vi = 0; float sum = 0.f;
    #pragma unroll
    for (int r = 0; r < 6; ++r) {
      int i = lane + r * 64;
      if (i < HW) {
        float x = base[i];
        sum += x;
        if (x > v) { v = x; vi = i; }   // strict > keeps first occurrence
      }
    }
    #pragma unroll
    for (int m = 1; m < 64; m <<= 1) {
      float v2 = __shfl_xor(v, m);
      int   i2 = __shfl_xor(vi, m);
      float s2 = __shfl_xor(sum, m);
      if (v2 > v || (v2 == v && i2 < vi)) { v = v2; vi = i2; }  // min idx on tie
      sum += s2;
    }
    if (lane == 0) {
      s_idx[wave] = vi;
      s_mov[wave] = (sum > 0.5f) ? 1.f : 0.f;
    }
  }
  __syncthreads();

  if (tid < 192) {
    const int c = tid;                // rows c and c+192
    const int   i0 = s_idx[4], i1 = s_idx[3], i2 = s_idx[2],
                i3 = s_idx[1], i4 = s_idx[0];
    const float m0 = s_mov[4], m1 = s_mov[3], m2 = s_mov[2],
                m3 = s_mov[1], m4 = s_mov[0];

    const float* ta = trunk + ((size_t)n * C_TRUNK + c) * HW;
    const float* tb = ta + (size_t)192 * HW;
    float a0 = ta[i0], a1 = ta[i1], a2 = ta[i2], a3 = ta[i3], a4 = ta[i4];
    float b0 = tb[i0], b1 = tb[i1], b2 = tb[i2], b3 = tb[i3], b4 = tb[i4];

    ushort* so = seq + (size_t)n * NHIST * C_TRUNK + c;
    so[0 * C_TRUNK]       = f2bf(a0 * m0);   // seq[t] = feats[4-t]
    so[1 * C_TRUNK]       = f2bf(a1 * m1);
    so[2 * C_TRUNK]       = f2bf(a2 * m2);
    so[3 * C_TRUNK]       = f2bf(a3 * m3);
    so[4 * C_TRUNK]       = f2bf(a4 * m4);
    so[0 * C_TRUNK + 192] = f2bf(b0 * m0);
    so[1 * C_TRUNK + 192] = f2bf(b1 * m1);
    so[2 * C_TRUNK + 192] = f2bf(b2 * m2);
    so[3 * C_TRUNK + 192] = f2bf(b3 * m3);
    so[4 * C_TRUNK + 192] = f2bf(b4 * m4);
  }
}

// -------- Kernel 2: G = seq @ w_ih^T + b_ih + b_hh  (bf16 MFMA, bf16 out) ----
__global__ __launch_bounds__(256) void gates_kernel(
    const ushort* __restrict__ seq,    // (5120, 384) bf16
    const ushort* __restrict__ w_ihb,  // (512, 384) bf16
    const float*  __restrict__ b_ih,   // (512)
    const float*  __restrict__ b_hh,   // (512)
    ushort* __restrict__ G)            // (5120, 512) bf16
{
  __shared__ ushort As[64][40];
  __shared__ ushort Bs[64][40];
  const int tid  = threadIdx.x;
  const int wv   = tid >> 6;
  const int lane = tid & 63;
  const int m0 = blockIdx.y * 64;
  const int j0 = blockIdx.x * 64;
  const int row_l = tid >> 2;
  const int koff  = (tid & 3) * 8;

  float4v acc0 = {0.f,0.f,0.f,0.f};
  float4v acc1 = {0.f,0.f,0.f,0.f};
  float4v acc2 = {0.f,0.f,0.f,0.f};
  float4v acc3 = {0.f,0.f,0.f,0.f};

  const int fr = lane & 15;
  const int fk = (lane >> 4) * 8;

  for (int k0 = 0; k0 < C_TRUNK; k0 += 32) {
    *(short8v*)&As[row_l][koff] =
        *(const short8v*)(seq + (size_t)(m0 + row_l) * C_TRUNK + k0 + koff);
    *(short8v*)&Bs[row_l][koff] =
        *(const short8v*)(w_ihb + (size_t)(j0 + row_l) * C_TRUNK + k0 + koff);
    __syncthreads();

    short8v af  = *(const short8v*)&As[wv * 16 + fr][fk];
    short8v bf0 = *(const short8v*)&Bs[ 0 + fr][fk];
    short8v bf1 = *(const short8v*)&Bs[16 + fr][fk];
    short8v bf2 = *(const short8v*)&Bs[32 + fr][fk];
    short8v bf3 = *(const short8v*)&Bs[48 + fr][fk];
    acc0 = __builtin_amdgcn_mfma_f32_16x16x32_bf16(af, bf0, acc0, 0, 0, 0);
    acc1 = __builtin_amdgcn_mfma_f32_16x16x32_bf16(af, bf1, acc1, 0, 0, 0);
    acc2 = __builtin_amdgcn_mfma_f32_16x16x32_bf16(af, bf2, acc2, 0, 0, 0);
    acc3 = __builtin_amdgcn_mfma_f32_16x16x32_bf16(af, bf3, acc3, 0, 0, 0);
    __syncthreads();
  }

  const int rbase = m0 + wv * 16 + (lane >> 4) * 4;
  #pragma unroll
  for (int j = 0; j < 4; ++j) {
    const float4v a = (j == 0) ? acc0 : (j == 1) ? acc1 : (j == 2) ? acc2 : acc3;
    const int cj = j0 + j * 16 + fr;
    const float bsum = b_ih[cj] + b_hh[cj];
    #pragma unroll
    for (int r = 0; r < 4; ++r)
      G[(size_t)(rbase + r) * NGATE + cj] = f2bf(a[r] + bsum);
  }
}

// -------- Kernel 3: recurrence + projection via MFMA -------------------------
// 4 samples/block, 512 threads = 8 waves. Samples in rows 0-3 of the 16-row
// fragment. Wave w owns gate cols w*64..+63; w_hh frags in regs; h carried
// bf16 in hswz[ks][lane][8] (lane-contiguous conflict-free b128 reads).
__global__ __launch_bounds__(512, 2) void lstm_kernel(
    const ushort* __restrict__ G,      // (5120, 512) bf16
    const float* __restrict__ w_hh,    // (512, 128)
    const float* __restrict__ w_proj,  // (384, 128)
    const float* __restrict__ b_proj,  // (384)
    float* __restrict__ out)           // (1024, 384)
{
  const int n0   = blockIdx.x * 4;
  const int tid  = threadIdx.x;
  const int wv   = tid >> 6;       // 0..7
  const int lane = tid & 63;
  const int fr   = lane & 15;
  const int fq   = lane >> 4;      // 0..3

  __shared__ ushort hswz[4][64][8];   // [ks][lane][q]  4 KB
  __shared__ float  glds[NGATE][4];   // [gate col][sample]  8 KB

  ((ushort4*)hswz)[tid] = make_ushort4(0, 0, 0, 0);

  const int j0w = wv * 64;
  short8v bfrag[4][4];                // [colfrag][ks]
  #pragma unroll
  for (int f = 0; f < 4; ++f)
    #pragma unroll
    for (int ks = 0; ks < 4; ++ks) {
      const float* wr = w_hh + (size_t)(j0w + f*16 + fr) * HID + ks*32 + fq*8;
      float4 lo = *(const float4*)wr;
      float4 hi = *(const float4*)(wr + 4);
      short8v b;
      b[0]=(short)f2bf(lo.x); b[1]=(short)f2bf(lo.y);
      b[2]=(short)f2bf(lo.z); b[3]=(short)f2bf(lo.w);
      b[4]=(short)f2bf(hi.x); b[5]=(short)f2bf(hi.y);
      b[6]=(short)f2bf(hi.z); b[7]=(short)f2bf(hi.w);
      bfrag[f][ks] = b;
    }

  // G prefetch as MFMA C-init (bf16 -> f32): sample r in lanes fq==0, reg r
  float4v gpre[NHIST][4];
  #pragma unroll
  for (int t = 0; t < NHIST; ++t)
    #pragma unroll
    for (int f = 0; f < 4; ++f) {
      float4v v = {0.f, 0.f, 0.f, 0.f};
      if (fq == 0) {
        const int col = j0w + f*16 + fr;
        #pragma unroll
        for (int r = 0; r < 4; ++r)
          v[r] = bf2f(G[((size_t)(n0 + r) * NHIST + t) * NGATE + col]);
      }
      gpre[t][f] = v;
    }

  float c4[4] = {0.f, 0.f, 0.f, 0.f};
  __syncthreads();

  #pragma unroll
  for (int t = 0; t < NHIST; ++t) {
    short8v af0 = *(const short8v*)&hswz[0][lane][0];
    short8v af1 = *(const short8v*)&hswz[1][lane][0];
    short8v af2 = *(const short8v*)&hswz[2][lane][0];
    short8v af3 = *(const short8v*)&hswz[3][lane][0];
    #pragma unroll
    for (int f = 0; f < 4; ++f) {
      float4v acc = gpre[t][f];
      acc = __builtin_amdgcn_mfma_f32_16x16x32_bf16(af0, bfrag[f][0], acc, 0, 0, 0);
      acc = __builtin_amdgcn_mfma_f32_16x16x32_bf16(af1, bfrag[f][1], acc, 0, 0, 0);
      acc = __builtin_amdgcn_mfma_f32_16x16x32_bf16(af2, bfrag[f][2], acc, 0, 0, 0);
      acc = __builtin_amdgcn_mfma_f32_16x16x32_bf16(af3, bfrag[f][3], acc, 0, 0, 0);
      if (fq == 0)
        *(float4v*)&glds[j0w + f*16 + fr][0] = acc;
    }
    __syncthreads();

    if (tid < HID) {
      const int j = tid;
      float4 iv = *(const float4*)&glds[      j][0];
      float4 fv = *(const float4*)&glds[128 + j][0];
      float4 gv = *(const float4*)&glds[256 + j][0];
      float4 ov = *(const float4*)&glds[384 + j][0];
      float ia[4] = {iv.x, iv.y, iv.z, iv.w};
      float fa[4] = {fv.x, fv.y, fv.z, fv.w};
      float ga[4] = {gv.x, gv.y, gv.z, gv.w};
      float oa[4] = {ov.x, ov.y, ov.z, ov.w};
      #pragma unroll
      for (int s = 0; s < 4; ++s) {
        float ig = 1.f / (1.f + __expf(-ia[s]));
        float fg = 1.f / (1.f + __expf(-fa[s]));
        float og = 1.f / (1.f + __expf(-oa[s]));
        c4[s] = fg * c4[s] + ig * tanhf(ga[s]);
        float h = og * tanhf(c4[s]);
        hswz[j >> 5][((j >> 3) & 3) * 16 + s][j & 7] = f2bf(h);
      }
    }
    __syncthreads();
  }

  const int j0p = wv * 48;
  short8v pfrag[3][4];
  #pragma unroll
  for (int f = 0; f < 3; ++f)
    #pragma unroll
    for (int ks = 0; ks < 4; ++ks) {
      const float* wr = w_proj + (size_t)(j0p + f*16 + fr) * HID + ks*32 + fq*8;
      float4 lo = *(const float4*)wr;
      float4 hi = *(const float4*)(wr + 4);
      short8v b;
      b[0]=(short)f2bf(lo.x); b[1]=(short)f2bf(lo.y);
      b[2]=(short)f2bf(lo.z); b[3]=(short)f2bf(lo.w);
      b[4]=(short)f2bf(hi.x); b[5]=(short)f2bf(hi.y);
      b[6]=(short)f2bf(hi.z); b[7]=(short)f2bf(hi.w);
      pfrag[f][ks] = b;
    }

  short8v hf0 = *(const short8v*)&hswz[0][lane][0];
  short8v hf1 = *(const short8v*)&hswz[1][lane][0];
  short8v hf2 = *(const short8v*)&hswz[2][lane][0];
  short8v hf3 = *(const short8v*)&hswz[3][lane][0];
  #pragma unroll
  for (int f = 0; f < 3; ++f) {
    const int col = j0p + f * 16 + fr;
    const float bp = b_proj[col];
    float4v acc = {bp, bp, bp, bp};
    acc = __builtin_amdgcn_mfma_f32_16x16x32_bf16(hf0, pfrag[f][0], acc, 0, 0, 0);
    acc = __builtin_amdgcn_mfma_f32_16x16x32_bf16(hf1, pfrag[f][1], acc, 0, 0, 0);
    acc = __builtin_amdgcn_mfma_f32_16x16x32_bf16(hf2, pfrag[f][2], acc, 0, 0, 0);
    acc = __builtin_amdgcn_mfma_f32_16x16x32_bf16(hf3, pfrag[f][3], acc, 0, 0, 0);
    if (fq == 0) {
      #pragma unroll
      for (int r = 0; r < 4; ++r)
        out[(size_t)(n0 + r) * C_TRUNK + col] = acc[r];
    }
  }
}

extern "C" void kernel_launch(void* const* d_in, const int* in_sizes, int n_in,
                              void* d_out, int out_size, void* d_ws, size_t ws_size,
                              hipStream_t stream) {
  const float* inp    = (const float*)d_in[0];
  const float* trunk  = (const float*)d_in[1];
  const float* w_ih   = (const float*)d_in[2];
  const float* w_hh   = (const float*)d_in[3];
  const float* b_ih   = (const float*)d_in[4];
  const float* b_hh   = (const float*)d_in[5];
  const float* w_proj = (const float*)d_in[6];
  const float* b_proj = (const float*)d_in[7];
  float* out = (float*)d_out;

  char* ws = (char*)d_ws;
  ushort* w_ihb = (ushort*)ws;                       // 512*384 bf16 (393216 B)
  ushort* seq   = (ushort*)(ws + 393216);            // 5120*384 bf16 (3932160 B)
  ushort* G     = (ushort*)(ws + 393216 + 3932160);  // 5120*512 bf16 (5242880 B)

  prep_kernel<<<N_SAMP, 384, 0, stream>>>(inp, w_ih, trunk, w_ihb, seq);
  gates_kernel<<<dim3(NGATE / 64, (N_SAMP * NHIST) / 64), 256, 0, stream>>>(
      seq, w_ihb, b_ih, b_hh, G);
  lstm_kernel<<<N_SAMP / 4, 512, 0, stream>>>(G, w_hh, w_proj, b_proj, out);
}

// Round 10
// 71.910 us; speedup vs baseline: 1.0910x; 1.0910x over previous
//
#include <hip/hip_runtime.h>
#include <hip/hip_bf16.h>
#include <float.h>

#define N_SAMP   1024
#define C_IN     22
#define HW       361
#define C_TRUNK  384
#define HID      128
#define NHIST    5
#define HIST_START 9
#define NGATE    512   // 4*HID

typedef __attribute__((ext_vector_type(8))) short short8v;
typedef __attribute__((ext_vector_type(4))) float float4v;

static __device__ __forceinline__ ushort f2bf(float x) {
  unsigned int b = __float_as_uint(x);
  b += 0x7fffu + ((b >> 16) & 1u);
  return (ushort)(b >> 16);
}
static __device__ __forceinline__ float bf2f(ushort u) {
  return __uint_as_float(((unsigned int)u) << 16);
}

#define WIH_ELEMS   (NGATE * C_TRUNK)          // 196608
#define WHH_ELEMS   (NGATE * HID)              // 65536
#define WPROJ_ELEMS (C_TRUNK * HID)            // 49152

// -------- Kernel 1: fused argmax + gather (+ all-weights bf16 precvt) --------
// 1024 blocks x 384 threads. Phase 1: waves 0..4 reduce history plane t via
// shuffle butterfly. Phase 2: threads 0..191 gather rows {c, c+192} (10
// scattered loads in flight, same 1444B trunk rows). Each thread also
// converts one element of {w_ih,w_hh,w_proj} to bf16 (311296 <= 393216 slots).
__global__ __launch_bounds__(384) void prep_kernel(
    const float* __restrict__ inp,     // (N, 22, 361)
    const float* __restrict__ w_ih,    // (512, 384)
    const float* __restrict__ w_hh,    // (512, 128)
    const float* __restrict__ w_proj,  // (384, 128)
    const float* __restrict__ trunk,   // (N, 384, 361)
    ushort* __restrict__ w_ihb,        // (512, 384) bf16
    ushort* __restrict__ w_hhb,        // (512, 128) bf16
    ushort* __restrict__ w_projb,      // (384, 128) bf16
    ushort* __restrict__ seq)          // (N, 5, 384) bf16, reversed + masked
{
  const int n    = blockIdx.x;
  const int tid  = threadIdx.x;
  const int wave = tid >> 6;   // 0..5
  const int lane = tid & 63;
  __shared__ int   s_idx[NHIST];
  __shared__ float s_mov[NHIST];

  // weight bf16 pre-conversion, one element per thread slot
  {
    const int g = n * 384 + tid;
    if (g < WIH_ELEMS) {
      w_ihb[g] = f2bf(w_ih[g]);
    } else if (g < WIH_ELEMS + WHH_ELEMS) {
      const int o = g - WIH_ELEMS;
      w_hhb[o] = f2bf(w_hh[o]);
    } else if (g < WIH_ELEMS + WHH_ELEMS + WPROJ_ELEMS) {
      const int o = g - WIH_ELEMS - WHH_ELEMS;
      w_projb[o] = f2bf(w_proj[o]);
    }
  }

  if (wave < NHIST) {
    const float* base = inp + ((size_t)n * C_IN + HIST_START + wave) * HW;
    float v = -FLT_MAX; int vi = 0; float sum = 0.f;
    #pragma unroll
    for (int r = 0; r < 6; ++r) {
      int i = lane + r * 64;
      if (i < HW) {
        float x = base[i];
        sum += x;
        if (x > v) { v = x; vi = i; }   // strict > keeps first occurrence
      }
    }
    #pragma unroll
    for (int m = 1; m < 64; m <<= 1) {
      float v2 = __shfl_xor(v, m);
      int   i2 = __shfl_xor(vi, m);
      float s2 = __shfl_xor(sum, m);
      if (v2 > v || (v2 == v && i2 < vi)) { v = v2; vi = i2; }  // min idx on tie
      sum += s2;
    }
    if (lane == 0) {
      s_idx[wave] = vi;
      s_mov[wave] = (sum > 0.5f) ? 1.f : 0.f;
    }
  }
  __syncthreads();

  if (tid < 192) {
    const int c = tid;                // rows c and c+192
    const int   i0 = s_idx[4], i1 = s_idx[3], i2 = s_idx[2],
                i3 = s_idx[1], i4 = s_idx[0];
    const float m0 = s_mov[4], m1 = s_mov[3], m2 = s_mov[2],
                m3 = s_mov[1], m4 = s_mov[0];

    const float* ta = trunk + ((size_t)n * C_TRUNK + c) * HW;
    const float* tb = ta + (size_t)192 * HW;
    float a0 = ta[i0], a1 = ta[i1], a2 = ta[i2], a3 = ta[i3], a4 = ta[i4];
    float b0 = tb[i0], b1 = tb[i1], b2 = tb[i2], b3 = tb[i3], b4 = tb[i4];

    ushort* so = seq + (size_t)n * NHIST * C_TRUNK + c;
    so[0 * C_TRUNK]       = f2bf(a0 * m0);   // seq[t] = feats[4-t]
    so[1 * C_TRUNK]       = f2bf(a1 * m1);
    so[2 * C_TRUNK]       = f2bf(a2 * m2);
    so[3 * C_TRUNK]       = f2bf(a3 * m3);
    so[4 * C_TRUNK]       = f2bf(a4 * m4);
    so[0 * C_TRUNK + 192] = f2bf(b0 * m0);
    so[1 * C_TRUNK + 192] = f2bf(b1 * m1);
    so[2 * C_TRUNK + 192] = f2bf(b2 * m2);
    so[3 * C_TRUNK + 192] = f2bf(b3 * m3);
    so[4 * C_TRUNK + 192] = f2bf(b4 * m4);
  }
}

// -------- Kernel 2: G = seq @ w_ih^T + b_ih + b_hh  (bf16 MFMA, bf16 out) ----
__global__ __launch_bounds__(256) void gates_kernel(
    const ushort* __restrict__ seq,    // (5120, 384) bf16
    const ushort* __restrict__ w_ihb,  // (512, 384) bf16
    const float*  __restrict__ b_ih,   // (512)
    const float*  __restrict__ b_hh,   // (512)
    ushort* __restrict__ G)            // (5120, 512) bf16
{
  __shared__ ushort As[64][40];
  __shared__ ushort Bs[64][40];
  const int tid  = threadIdx.x;
  const int wv   = tid >> 6;
  const int lane = tid & 63;
  const int m0 = blockIdx.y * 64;
  const int j0 = blockIdx.x * 64;
  const int row_l = tid >> 2;
  const int koff  = (tid & 3) * 8;

  float4v acc0 = {0.f,0.f,0.f,0.f};
  float4v acc1 = {0.f,0.f,0.f,0.f};
  float4v acc2 = {0.f,0.f,0.f,0.f};
  float4v acc3 = {0.f,0.f,0.f,0.f};

  const int fr = lane & 15;
  const int fk = (lane >> 4) * 8;

  for (int k0 = 0; k0 < C_TRUNK; k0 += 32) {
    *(short8v*)&As[row_l][koff] =
        *(const short8v*)(seq + (size_t)(m0 + row_l) * C_TRUNK + k0 + koff);
    *(short8v*)&Bs[row_l][koff] =
        *(const short8v*)(w_ihb + (size_t)(j0 + row_l) * C_TRUNK + k0 + koff);
    __syncthreads();

    short8v af  = *(const short8v*)&As[wv * 16 + fr][fk];
    short8v bf0 = *(const short8v*)&Bs[ 0 + fr][fk];
    short8v bf1 = *(const short8v*)&Bs[16 + fr][fk];
    short8v bf2 = *(const short8v*)&Bs[32 + fr][fk];
    short8v bf3 = *(const short8v*)&Bs[48 + fr][fk];
    acc0 = __builtin_amdgcn_mfma_f32_16x16x32_bf16(af, bf0, acc0, 0, 0, 0);
    acc1 = __builtin_amdgcn_mfma_f32_16x16x32_bf16(af, bf1, acc1, 0, 0, 0);
    acc2 = __builtin_amdgcn_mfma_f32_16x16x32_bf16(af, bf2, acc2, 0, 0, 0);
    acc3 = __builtin_amdgcn_mfma_f32_16x16x32_bf16(af, bf3, acc3, 0, 0, 0);
    __syncthreads();
  }

  const int rbase = m0 + wv * 16 + (lane >> 4) * 4;
  #pragma unroll
  for (int j = 0; j < 4; ++j) {
    const float4v a = (j == 0) ? acc0 : (j == 1) ? acc1 : (j == 2) ? acc2 : acc3;
    const int cj = j0 + j * 16 + fr;
    const float bsum = b_ih[cj] + b_hh[cj];
    #pragma unroll
    for (int r = 0; r < 4; ++r)
      G[(size_t)(rbase + r) * NGATE + cj] = f2bf(a[r] + bsum);
  }
}

// -------- Kernel 3: recurrence + projection via MFMA (bf16 weights) ----------
// 4 samples/block, 512 threads = 8 waves. Samples in rows 0-3 of the 16-row
// fragment. Wave w owns gate cols w*64..+63; w_hh frags direct b128 loads from
// pre-converted bf16; h carried bf16 in hswz[ks][lane][8].
__global__ __launch_bounds__(512, 2) void lstm_kernel(
    const ushort* __restrict__ G,        // (5120, 512) bf16
    const ushort* __restrict__ w_hhb,    // (512, 128) bf16
    const ushort* __restrict__ w_projb,  // (384, 128) bf16
    const float*  __restrict__ b_proj,   // (384)
    float* __restrict__ out)             // (1024, 384)
{
  const int n0   = blockIdx.x * 4;
  const int tid  = threadIdx.x;
  const int wv   = tid >> 6;       // 0..7
  const int lane = tid & 63;
  const int fr   = lane & 15;
  const int fq   = lane >> 4;      // 0..3

  __shared__ ushort hswz[4][64][8];   // [ks][lane][q]  4 KB
  __shared__ float  glds[NGATE][4];   // [gate col][sample]  8 KB

  ((ushort4*)hswz)[tid] = make_ushort4(0, 0, 0, 0);

  const int j0w = wv * 64;
  short8v bfrag[4][4];                // [colfrag][ks]
  #pragma unroll
  for (int f = 0; f < 4; ++f)
    #pragma unroll
    for (int ks = 0; ks < 4; ++ks)
      bfrag[f][ks] = *(const short8v*)(
          w_hhb + (size_t)(j0w + f*16 + fr) * HID + ks*32 + fq*8);

  // G prefetch as MFMA C-init (bf16 -> f32): sample r in lanes fq==0, reg r
  float4v gpre[NHIST][4];
  #pragma unroll
  for (int t = 0; t < NHIST; ++t)
    #pragma unroll
    for (int f = 0; f < 4; ++f) {
      float4v v = {0.f, 0.f, 0.f, 0.f};
      if (fq == 0) {
        const int col = j0w + f*16 + fr;
        #pragma unroll
        for (int r = 0; r < 4; ++r)
          v[r] = bf2f(G[((size_t)(n0 + r) * NHIST + t) * NGATE + col]);
      }
      gpre[t][f] = v;
    }

  float c4[4] = {0.f, 0.f, 0.f, 0.f};
  __syncthreads();

  #pragma unroll
  for (int t = 0; t < NHIST; ++t) {
    short8v af0 = *(const short8v*)&hswz[0][lane][0];
    short8v af1 = *(const short8v*)&hswz[1][lane][0];
    short8v af2 = *(const short8v*)&hswz[2][lane][0];
    short8v af3 = *(const short8v*)&hswz[3][lane][0];
    #pragma unroll
    for (int f = 0; f < 4; ++f) {
      float4v acc = gpre[t][f];
      acc = __builtin_amdgcn_mfma_f32_16x16x32_bf16(af0, bfrag[f][0], acc, 0, 0, 0);
      acc = __builtin_amdgcn_mfma_f32_16x16x32_bf16(af1, bfrag[f][1], acc, 0, 0, 0);
      acc = __builtin_amdgcn_mfma_f32_16x16x32_bf16(af2, bfrag[f][2], acc, 0, 0, 0);
      acc = __builtin_amdgcn_mfma_f32_16x16x32_bf16(af3, bfrag[f][3], acc, 0, 0, 0);
      if (fq == 0)
        *(float4v*)&glds[j0w + f*16 + fr][0] = acc;
    }
    __syncthreads();

    if (tid < HID) {
      const int j = tid;
      float4 iv = *(const float4*)&glds[      j][0];
      float4 fv = *(const float4*)&glds[128 + j][0];
      float4 gv = *(const float4*)&glds[256 + j][0];
      float4 ov = *(const float4*)&glds[384 + j][0];
      float ia[4] = {iv.x, iv.y, iv.z, iv.w};
      float fa[4] = {fv.x, fv.y, fv.z, fv.w};
      float ga[4] = {gv.x, gv.y, gv.z, gv.w};
      float oa[4] = {ov.x, ov.y, ov.z, ov.w};
      #pragma unroll
      for (int s = 0; s < 4; ++s) {
        float ig = 1.f / (1.f + __expf(-ia[s]));
        float fg = 1.f / (1.f + __expf(-fa[s]));
        float og = 1.f / (1.f + __expf(-oa[s]));
        c4[s] = fg * c4[s] + ig * tanhf(ga[s]);
        float h = og * tanhf(c4[s]);
        hswz[j >> 5][((j >> 3) & 3) * 16 + s][j & 7] = f2bf(h);
      }
    }
    __syncthreads();
  }

  const int j0p = wv * 48;
  short8v pfrag[3][4];
  #pragma unroll
  for (int f = 0; f < 3; ++f)
    #pragma unroll
    for (int ks = 0; ks < 4; ++ks)
      pfrag[f][ks] = *(const short8v*)(
          w_projb + (size_t)(j0p + f*16 + fr) * HID + ks*32 + fq*8);

  short8v hf0 = *(const short8v*)&hswz[0][lane][0];
  short8v hf1 = *(const short8v*)&hswz[1][lane][0];
  short8v hf2 = *(const short8v*)&hswz[2][lane][0];
  short8v hf3 = *(const short8v*)&hswz[3][lane][0];
  #pragma unroll
  for (int f = 0; f < 3; ++f) {
    const int col = j0p + f * 16 + fr;
    const float bp = b_proj[col];
    float4v acc = {bp, bp, bp, bp};
    acc = __builtin_amdgcn_mfma_f32_16x16x32_bf16(hf0, pfrag[f][0], acc, 0, 0, 0);
    acc = __builtin_amdgcn_mfma_f32_16x16x32_bf16(hf1, pfrag[f][1], acc, 0, 0, 0);
    acc = __builtin_amdgcn_mfma_f32_16x16x32_bf16(hf2, pfrag[f][2], acc, 0, 0, 0);
    acc = __builtin_amdgcn_mfma_f32_16x16x32_bf16(hf3, pfrag[f][3], acc, 0, 0, 0);
    if (fq == 0) {
      #pragma unroll
      for (int r = 0; r < 4; ++r)
        out[(size_t)(n0 + r) * C_TRUNK + col] = acc[r];
    }
  }
}

extern "C" void kernel_launch(void* const* d_in, const int* in_sizes, int n_in,
                              void* d_out, int out_size, void* d_ws, size_t ws_size,
                              hipStream_t stream) {
  const float* inp    = (const float*)d_in[0];
  const float* trunk  = (const float*)d_in[1];
  const float* w_ih   = (const float*)d_in[2];
  const float* w_hh   = (const float*)d_in[3];
  const float* b_ih   = (const float*)d_in[4];
  const float* b_hh   = (const float*)d_in[5];
  const float* w_proj = (const float*)d_in[6];
  const float* b_proj = (const float*)d_in[7];
  float* out = (float*)d_out;

  char* ws = (char*)d_ws;
  ushort* w_ihb   = (ushort*)ws;                 // 196608*2 = 393216 B
  ushort* w_hhb   = (ushort*)(ws + 393216);      //  65536*2 = 131072 B
  ushort* w_projb = (ushort*)(ws + 524288);      //  49152*2 =  98304 B
  ushort* seq     = (ushort*)(ws + 622592);      // 5120*384*2 = 3932160 B
  ushort* G       = (ushort*)(ws + 4554752);     // 5120*512*2 = 5242880 B

  prep_kernel<<<N_SAMP, 384, 0, stream>>>(inp, w_ih, w_hh, w_proj, trunk,
                                          w_ihb, w_hhb, w_projb, seq);
  gates_kernel<<<dim3(NGATE / 64, (N_SAMP * NHIST) / 64), 256, 0, stream>>>(
      seq, w_ihb, b_ih, b_hh, G);
  lstm_kernel<<<N_SAMP / 4, 512, 0, stream>>>(G, w_hhb, w_projb, b_proj, out);
}